// Round 1
// 1075.216 us; speedup vs baseline: 1.0746x; 1.0746x over previous
//
#include <hip/hip_runtime.h>
#include <cmath>

typedef __bf16 bf16;
typedef __bf16 bf16x8 __attribute__((ext_vector_type(8)));
typedef float f32x4 __attribute__((ext_vector_type(4)));

#define B_ 2
#define S_ 2048
#define D_ 1024
#define H_ 16
#define HD_ 64
#define MLP_ 4096
#define XOUT_ ((size_t)B_ * S_ * D_)   // 4194304 elements

#define SBAR() __builtin_amdgcn_s_barrier()
#define VMCNT(N) asm volatile("s_waitcnt vmcnt(" #N ")" ::: "memory")
#define SFENCE() asm volatile("" ::: "memory")

__device__ __forceinline__ void gll16(const void* g, void* l) {
  __builtin_amdgcn_global_load_lds((const __attribute__((address_space(1))) void*)g,
                                   (__attribute__((address_space(3))) void*)l, 16, 0, 0);
}

__device__ __forceinline__ f32x4 mfma16(bf16x8 a, bf16x8 b, f32x4 c) {
  return __builtin_amdgcn_mfma_f32_16x16x32_bf16(a, b, c, 0, 0, 0);
}

__device__ __forceinline__ float bfu2f(unsigned short u) {
  return __uint_as_float(((unsigned int)u) << 16);
}
__device__ __forceinline__ unsigned short f2bu(float v) {
  union { bf16 b; unsigned short u; } c; c.b = (bf16)v; return c.u;
}
__device__ __forceinline__ float ld_sc(const void* p, size_t i, int f32) {
  return f32 ? ((const float*)p)[i] : bfu2f(((const unsigned short*)p)[i]);
}

// XOR-swizzled element offset within a [rows][64] bf16 tile (row stride 128B).
// byte ^= ((byte>>9)&3)<<5 : involution, spreads the 128B-row-stride column
// reads across all 8 LDS bank groups (T2).
__device__ __forceinline__ int swz(int row, int col) {
  int byo = row * 128 + col * 2;
  return (byo ^ (((byo >> 9) & 3) << 5)) >> 1;
}

// ---------------- dtype detector ----------------
__global__ __launch_bounds__(64) void detect_k(const unsigned short* __restrict__ x,
                                               int* __restrict__ flag) {
  int tid = threadIdx.x;
  int cnt = 0;
  for (int i = tid; i < 512; i += 64) {
    int e = (x[i] >> 7) & 0xFF;
    if (e >= 0xBF) cnt++;
  }
  #pragma unroll
  for (int d = 1; d < 64; d <<= 1) cnt += __shfl_xor(cnt, d);
  if (tid == 0) flag[0] = (cnt > 8) ? 1 : 0;
}

// ---------------- adaptive bf16 transpose ----------------
__global__ __launch_bounds__(256) void transpose_ad(const void* __restrict__ in,
                                                    unsigned short* __restrict__ out,
                                                    int R, int C,
                                                    const int* __restrict__ flagp) {
  __shared__ unsigned short t[64][68];
  const int f32 = flagp[0];
  const int tid = threadIdx.x;
  const int c0 = blockIdx.x * 64, r0 = blockIdx.y * 64;
  for (int i = tid * 4; i < 4096; i += 1024) {
    int rr = i >> 6, cc = i & 63;
    size_t off = (size_t)(r0 + rr) * C + c0 + cc;
    if (f32) {
      float4 f = *(const float4*)((const float*)in + off);
      t[rr][cc + 0] = f2bu(f.x); t[rr][cc + 1] = f2bu(f.y);
      t[rr][cc + 2] = f2bu(f.z); t[rr][cc + 3] = f2bu(f.w);
    } else {
      *(ushort4*)&t[rr][cc] = *(const ushort4*)((const unsigned short*)in + off);
    }
  }
  __syncthreads();
  for (int i = tid * 4; i < 4096; i += 1024) {
    int orr = i & 63, oc = i >> 6;
    ushort4 v;
    v.x = t[orr + 0][oc]; v.y = t[orr + 1][oc];
    v.z = t[orr + 2][oc]; v.w = t[orr + 3][oc];
    *(ushort4*)(out + (size_t)(c0 + oc) * R + r0 + orr) = v;
  }
}

// ---------------- V transpose ----------------
__global__ __launch_bounds__(256) void vtrans_k(const unsigned short* __restrict__ qkv,
                                                unsigned short* __restrict__ vT) {
  __shared__ unsigned short t[64][68];
  const int tid = threadIdx.x;
  const int s0 = blockIdx.x * 64, h = blockIdx.y, b = blockIdx.z;
  for (int i = tid * 4; i < 4096; i += 1024) {
    int si = i >> 6, hd = i & 63;
    *(ushort4*)&t[si][hd] =
        *(const ushort4*)(qkv + (size_t)(b * S_ + s0 + si) * 3072 + 2048 + h * 64 + hd);
  }
  __syncthreads();
  for (int i = tid * 4; i < 4096; i += 1024) {
    int ss = i & 63, hd = i >> 6;
    ushort4 v;
    v.x = t[ss + 0][hd]; v.y = t[ss + 1][hd];
    v.z = t[ss + 2][hd]; v.w = t[ss + 3][hd];
    *(ushort4*)(vT + ((size_t)(b * H_ + h) * 64 + hd) * S_ + s0 + ss) = v;
  }
}

// ---------------- LayerNorm ----------------
__global__ __launch_bounds__(256) void ln_k(const void* __restrict__ xv,
                                            const void* __restrict__ g,
                                            const void* __restrict__ bvec,
                                            bf16* __restrict__ out,
                                            const int* __restrict__ flagp,
                                            int force_xf32) {
  const int f32 = flagp[0];
  const int xf32 = force_xf32 ? 1 : f32;
  const int row = blockIdx.x, tid = threadIdx.x;
  float v[4];
  if (xf32) {
    float4 f = *(const float4*)((const float*)xv + (size_t)row * 1024 + tid * 4);
    v[0] = f.x; v[1] = f.y; v[2] = f.z; v[3] = f.w;
  } else {
    ushort4 u = *(const ushort4*)((const unsigned short*)xv + (size_t)row * 1024 + tid * 4);
    v[0] = bfu2f(u.x); v[1] = bfu2f(u.y); v[2] = bfu2f(u.z); v[3] = bfu2f(u.w);
  }
  float s = 0.f, q = 0.f;
  #pragma unroll
  for (int i = 0; i < 4; i++) { s += v[i]; q += v[i] * v[i]; }
  #pragma unroll
  for (int d = 1; d < 64; d <<= 1) { s += __shfl_xor(s, d); q += __shfl_xor(q, d); }
  __shared__ float red[8];
  if ((tid & 63) == 0) { red[(tid >> 6) * 2] = s; red[(tid >> 6) * 2 + 1] = q; }
  __syncthreads();
  s = red[0] + red[2] + red[4] + red[6];
  q = red[1] + red[3] + red[5] + red[7];
  const float mean = s * (1.0f / 1024.0f);
  const float var = q * (1.0f / 1024.0f) - mean * mean;
  const float rs = rsqrtf(var + 1e-5f);
  unsigned short ov[4];
  #pragma unroll
  for (int i = 0; i < 4; i++) {
    float gg = ld_sc(g, tid * 4 + i, f32);
    float bb = ld_sc(bvec, tid * 4 + i, f32);
    ov[i] = f2bu((v[i] - mean) * rs * gg + bb);
  }
  ushort4 o4; o4.x = ov[0]; o4.y = ov[1]; o4.z = ov[2]; o4.w = ov[3];
  *(ushort4*)((unsigned short*)out + (size_t)row * 1024 + tid * 4) = o4;
}

// ---------------- GEMM (unchanged structure; GELU now via exp2) ----------------
template <int MODE>
__global__ __launch_bounds__(256) void gemm_bt(const bf16* __restrict__ A,
                                               const bf16* __restrict__ BT,
                                               int N, int K,
                                               const void* __restrict__ bias,
                                               const void* __restrict__ resb,
                                               const float* __restrict__ resf,
                                               bf16* __restrict__ outb,
                                               float* __restrict__ outf,
                                               const int* __restrict__ flagp) {
  __shared__ __align__(16) bf16 sA[128 * 64];
  __shared__ __align__(16) bf16 sB[128 * 64];
  const int f32 = flagp[0];
  const int tid = threadIdx.x;
  const int lane = tid & 63;
  const int wave = tid >> 6;
  const int wm = wave >> 1, wn = wave & 1;
  const int m0 = blockIdx.y * 128, n0 = blockIdx.x * 128;
  const int cn = lane & 15, rl = lane >> 4;
  const int r0 = tid >> 3, c16 = tid & 7;

  f32x4 zero = {0.f, 0.f, 0.f, 0.f};
  f32x4 acc[4][4];
  #pragma unroll
  for (int i = 0; i < 4; i++)
    #pragma unroll
    for (int j = 0; j < 4; j++) acc[i][j] = zero;

  for (int k0 = 0; k0 < K; k0 += 64) {
    __syncthreads();
    #pragma unroll
    for (int i = 0; i < 4; i++) {
      int row = r0 + i * 32;
      gll16(A + (size_t)(m0 + row) * K + k0 + c16 * 8, &sA[row * 64 + c16 * 8]);
      gll16(BT + (size_t)(n0 + row) * K + k0 + c16 * 8, &sB[row * 64 + c16 * 8]);
    }
    __syncthreads();
    #pragma unroll
    for (int kk = 0; kk < 64; kk += 32) {
      bf16x8 af[4], bfr[4];
      #pragma unroll
      for (int t = 0; t < 4; t++) {
        af[t] = *(const bf16x8*)&sA[(wm * 64 + t * 16 + cn) * 64 + kk + rl * 8];
        bfr[t] = *(const bf16x8*)&sB[(wn * 64 + t * 16 + cn) * 64 + kk + rl * 8];
      }
      #pragma unroll
      for (int mt = 0; mt < 4; mt++)
        #pragma unroll
        for (int nt = 0; nt < 4; nt++)
          acc[mt][nt] = mfma16(af[mt], bfr[nt], acc[mt][nt]);
    }
  }

  #pragma unroll
  for (int mt = 0; mt < 4; mt++) {
    #pragma unroll
    for (int nt = 0; nt < 4; nt++) {
      #pragma unroll
      for (int j = 0; j < 4; j++) {
        const int row = m0 + wm * 64 + mt * 16 + rl * 4 + j;
        const int col = n0 + wn * 64 + nt * 16 + cn;
        const size_t idx = (size_t)row * N + col;
        float v = acc[mt][nt][j];
        if (MODE == 0) {
          outb[idx] = (bf16)v;
        } else if (MODE == 1) {
          v += ld_sc(bias, col, f32);
          // gelu(v) = v * 0.5*(1+tanh(u)) = v / (1 + exp2(-2*log2e*u))
          float u = 0.7978845608028654f * (v + 0.044715f * v * v * v);
          float gl = v / (1.0f + exp2f(-2.8853900817779268f * u));
          outb[idx] = (bf16)gl;
        } else if (MODE == 2) {
          outf[idx] = v + ld_sc(resb, idx, f32);
        } else {
          float val = v + ld_sc(bias, col, f32) + resf[idx];
          if (f32) outf[idx] = val; else outb[idx] = (bf16)val;
        }
      }
    }
  }
}

// ---------------- Attention: pipelined 2-pass, swizzled LDS, exp2 softmax ----------------
__global__ __launch_bounds__(256) void attn_k(const bf16* __restrict__ qkv,
                                              const bf16* __restrict__ vT,
                                              void* __restrict__ Pv,
                                              bf16* __restrict__ ao,
                                              const int* __restrict__ flagp) {
  __shared__ __align__(16) bf16 sK[2][64 * 64];
  __shared__ __align__(16) bf16 sV[2][64 * 64];
  __shared__ __align__(16) bf16 sP[4][16 * 64];   // total LDS = 40960B -> 4 blocks/CU
  const int f32o = flagp[0];
  const int tid = threadIdx.x, lane = tid & 63, wave = tid >> 6;
  const int qt = (int)(gridDim.x - 1 - blockIdx.x);  // LPT: heavy blocks dispatch first
  const int h = blockIdx.y, b = blockIdx.z;
  const float scale2 = 0.18033688011112042f;  // 0.125 * log2(e); softmax base-2 == base-e
  const float NEG = -1e30f;
  const int cn = lane & 15, rl = lane >> 4;

  // staging: LDS dest is linear (gll requirement); global SOURCE is pre-swizzled
  // so that swz() reads see logical [row][col] (rule: both-sides-or-neither).
  int urow[2], ucol[2], ldst[2];
  #pragma unroll
  for (int i = 0; i < 2; i++) {
    int Lb = tid * 16 + i * 4096;
    int Ub = Lb ^ (((Lb >> 9) & 3) << 5);
    urow[i] = Ub >> 7;
    ucol[i] = (Ub & 127) >> 1;
    ldst[i] = Lb >> 1;
  }

  const bf16* kbase = qkv + (size_t)b * S_ * 3072 + 1024 + h * 64;
  const bf16* vbase = vT + ((size_t)(b * H_ + h) * 64) * S_;

  // Q fragments live in registers for the whole kernel (no sQ)
  bf16x8 aq[2];
  {
    const bf16* qb = qkv + (size_t)(b * S_ + qt * 64 + wave * 16 + cn) * 3072 + h * 64;
    aq[0] = *(const bf16x8*)(qb + rl * 8);
    aq[1] = *(const bf16x8*)(qb + 32 + rl * 8);
  }

  // ---- pass 1 prologue
  #pragma unroll
  for (int i = 0; i < 2; i++)
    gll16(kbase + (size_t)urow[i] * 3072 + ucol[i], &sK[0][ldst[i]]);
  VMCNT(0);
  SBAR();

  float m_i[4], l_i[4];
  #pragma unroll
  for (int j = 0; j < 4; j++) { m_i[j] = NEG; l_i[j] = 0.0f; }

  int cur = 0;
  for (int kt = 0; kt <= qt; kt++) {
    if (kt < qt) {
      #pragma unroll
      for (int i = 0; i < 2; i++)
        gll16(kbase + (size_t)((kt + 1) * 64 + urow[i]) * 3072 + ucol[i], &sK[cur ^ 1][ldst[i]]);
      SFENCE();
    }
    f32x4 s[4];
    f32x4 zero = {0.f, 0.f, 0.f, 0.f};
    #pragma unroll
    for (int nt = 0; nt < 4; nt++) s[nt] = zero;
    #pragma unroll
    for (int kx = 0; kx < 2; kx++)
      #pragma unroll
      for (int nt = 0; nt < 4; nt++) {
        bf16x8 bb = *(const bf16x8*)&sK[cur][swz(nt * 16 + cn, kx * 32 + rl * 8)];
        s[nt] = mfma16(aq[kx], bb, s[nt]);
      }
    float pm[4] = {NEG, NEG, NEG, NEG};
    if (kt == qt) {  // only the diagonal tile needs masking
      #pragma unroll
      for (int nt = 0; nt < 4; nt++)
        #pragma unroll
        for (int j = 0; j < 4; j++) {
          float v = (nt * 16 + cn > wave * 16 + rl * 4 + j) ? NEG : s[nt][j] * scale2;
          s[nt][j] = v;
          pm[j] = fmaxf(pm[j], v);
        }
    } else {
      #pragma unroll
      for (int nt = 0; nt < 4; nt++)
        #pragma unroll
        for (int j = 0; j < 4; j++) {
          float v = s[nt][j] * scale2;
          s[nt][j] = v;
          pm[j] = fmaxf(pm[j], v);
        }
    }
    #pragma unroll
    for (int j = 0; j < 4; j++) {
      #pragma unroll
      for (int d = 1; d < 16; d <<= 1) pm[j] = fmaxf(pm[j], __shfl_xor(pm[j], d));
      float mn = fmaxf(m_i[j], pm[j]);
      float ps = exp2f(s[0][j] - mn) + exp2f(s[1][j] - mn) +
                 exp2f(s[2][j] - mn) + exp2f(s[3][j] - mn);
      #pragma unroll
      for (int d = 1; d < 16; d <<= 1) ps += __shfl_xor(ps, d);
      l_i[j] = l_i[j] * exp2f(m_i[j] - mn) + ps;
      m_i[j] = mn;
    }
    if (kt < qt) { VMCNT(0); SBAR(); cur ^= 1; }
  }

  float inv_l[4];
  #pragma unroll
  for (int j = 0; j < 4; j++) inv_l[j] = 1.0f / l_i[j];

  // ---- pass 2 prologue
  SBAR();  // all waves done reading pass-1 K buffers
  #pragma unroll
  for (int i = 0; i < 2; i++) {
    gll16(kbase + (size_t)urow[i] * 3072 + ucol[i], &sK[0][ldst[i]]);
    gll16(vbase + (size_t)urow[i] * S_ + ucol[i], &sV[0][ldst[i]]);
  }
  VMCNT(0);
  SBAR();
  cur = 0;

  f32x4 o[4];
  {
    f32x4 zero = {0.f, 0.f, 0.f, 0.f};
    #pragma unroll
    for (int nt = 0; nt < 4; nt++) o[nt] = zero;
  }

  for (int kt = 0; kt <= qt; kt++) {
    if (kt < qt) {
      #pragma unroll
      for (int i = 0; i < 2; i++) {
        gll16(kbase + (size_t)((kt + 1) * 64 + urow[i]) * 3072 + ucol[i], &sK[cur ^ 1][ldst[i]]);
        gll16(vbase + (size_t)urow[i] * S_ + (kt + 1) * 64 + ucol[i], &sV[cur ^ 1][ldst[i]]);
      }
      SFENCE();  // pin the 4 stage loads first in the vmcnt FIFO
    }
    // QK^T (recompute)
    f32x4 s[4];
    f32x4 zero = {0.f, 0.f, 0.f, 0.f};
    #pragma unroll
    for (int nt = 0; nt < 4; nt++) s[nt] = zero;
    #pragma unroll
    for (int kx = 0; kx < 2; kx++)
      #pragma unroll
      for (int nt = 0; nt < 4; nt++) {
        bf16x8 bb = *(const bf16x8*)&sK[cur][swz(nt * 16 + cn, kx * 32 + rl * 8)];
        s[nt] = mfma16(aq[kx], bb, s[nt]);
      }
    // P -> sP (bf16, swizzled; intra-wave only, no barrier needed)
    if (kt == qt) {
      #pragma unroll
      for (int nt = 0; nt < 4; nt++)
        #pragma unroll
        for (int j = 0; j < 4; j++) {
          bool masked = (nt * 16 + cn > wave * 16 + rl * 4 + j);
          float p = masked ? 0.0f : exp2f(s[nt][j] * scale2 - m_i[j]) * inv_l[j];
          sP[wave][swz(rl * 4 + j, nt * 16 + cn)] = (bf16)p;
        }
    } else {
      #pragma unroll
      for (int nt = 0; nt < 4; nt++)
        #pragma unroll
        for (int j = 0; j < 4; j++) {
          float p = exp2f(s[nt][j] * scale2 - m_i[j]) * inv_l[j];
          sP[wave][swz(rl * 4 + j, nt * 16 + cn)] = (bf16)p;
        }
    }
    // P tile -> global (early, so stores drain under PV compute)
    {
      size_t base = XOUT_ + (((size_t)b * H_ + h) * S_ + qt * 64 + wave * 16) * S_ + kt * 64;
      #pragma unroll
      for (int i = 0; i < 2; i++) {
        int idx = lane + i * 64;
        int r = idx >> 3, cc = idx & 7;
        uint4 val = *(const uint4*)&sP[wave][swz(r, cc * 8)];
        if (f32o) {
          float4 lo, hi;
          lo.x = __uint_as_float(val.x << 16); lo.y = __uint_as_float(val.x & 0xffff0000u);
          lo.z = __uint_as_float(val.y << 16); lo.w = __uint_as_float(val.y & 0xffff0000u);
          hi.x = __uint_as_float(val.z << 16); hi.y = __uint_as_float(val.z & 0xffff0000u);
          hi.z = __uint_as_float(val.w << 16); hi.w = __uint_as_float(val.w & 0xffff0000u);
          *(float4*)((float*)Pv + base + (size_t)r * S_ + cc * 8) = lo;
          *(float4*)((float*)Pv + base + (size_t)r * S_ + cc * 8 + 4) = hi;
        } else {
          *(uint4*)((bf16*)Pv + base + (size_t)r * S_ + cc * 8) = val;
        }
      }
    }
    // PV
    #pragma unroll
    for (int kx = 0; kx < 2; kx++) {
      bf16x8 ap = *(const bf16x8*)&sP[wave][swz(cn, kx * 32 + rl * 8)];
      #pragma unroll
      for (int nt = 0; nt < 4; nt++) {
        bf16x8 bv = *(const bf16x8*)&sV[cur][swz(nt * 16 + cn, kx * 32 + rl * 8)];
        o[nt] = mfma16(ap, bv, o[nt]);
      }
    }
    if (kt < qt) {
      // counted wait: retire the 4 stage loads; leave our P stores in flight
      if (f32o) { VMCNT(4); } else { VMCNT(2); }
      SBAR();
      cur ^= 1;
    }
  }

  // zero-fill strictly-above-diagonal tiles
  {
    const int t0 = qt + 1;
    const int nch = (32 - t0) * 8;
    size_t rowbase = XOUT_ + (((size_t)b * H_ + h) * S_ + qt * 64) * S_;
    uint4 z; z.x = 0; z.y = 0; z.z = 0; z.w = 0;
    for (int idx = tid; idx < 64 * nch; idx += 256) {
      int r = idx / nch, cc = idx % nch;
      size_t off = rowbase + (size_t)r * S_ + t0 * 64 + cc * 8;
      if (f32o) {
        *(uint4*)((float*)Pv + off) = z;
        *(uint4*)((float*)Pv + off + 4) = z;
      } else {
        *(uint4*)((bf16*)Pv + off) = z;
      }
    }
  }

  // write O (internal, bf16)
  #pragma unroll
  for (int nt = 0; nt < 4; nt++)
    #pragma unroll
    for (int j = 0; j < 4; j++) {
      int rowg2 = b * S_ + qt * 64 + wave * 16 + rl * 4 + j;
      ao[(size_t)rowg2 * 1024 + h * 64 + nt * 16 + cn] = (bf16)o[nt][j];
    }
}

extern "C" void kernel_launch(void* const* d_in, const int* in_sizes, int n_in,
                              void* d_out, int out_size, void* d_ws, size_t ws_size,
                              hipStream_t stream) {
  (void)in_sizes; (void)n_in; (void)out_size; (void)ws_size;
  const void* x    = d_in[0];
  const void* ln1g = d_in[1];
  const void* ln1b = d_in[2];
  const void* Wq   = d_in[3];
  const void* Wk   = d_in[4];
  const void* Wv   = d_in[5];
  const void* Wo   = d_in[6];
  const void* ln2g = d_in[7];
  const void* ln2b = d_in[8];
  const void* fc1w = d_in[9];
  const void* fc1b = d_in[10];
  const void* fc2w = d_in[11];
  const void* fc2b = d_in[12];

  char* ws = (char*)d_ws;
  bf16* wqkvT = (bf16*)(ws + 0);
  bf16* woT   = (bf16*)(ws + 6291456);
  bf16* fc1T  = (bf16*)(ws + 8388608);
  bf16* fc2T  = (bf16*)(ws + 16777216);
  bf16* h     = (bf16*)(ws + 25165824);
  bf16* qkv   = (bf16*)(ws + 33554432);
  bf16* vT    = (bf16*)(ws + 58720256);
  bf16* m1    = (bf16*)(ws + 33554432);
  bf16* aout  = (bf16*)(ws + 67108864);
  float* x1   = (float*)(ws + 75497472);
  int* flag   = (int*)(ws + 92274688);

  dim3 blk(256);

  detect_k<<<1, 64, 0, stream>>>((const unsigned short*)x, flag);

  transpose_ad<<<dim3(16, 16), blk, 0, stream>>>(Wq, (unsigned short*)wqkvT, 1024, 1024, flag);
  transpose_ad<<<dim3(16, 16), blk, 0, stream>>>(Wk, (unsigned short*)(wqkvT + 1024 * 1024), 1024, 1024, flag);
  transpose_ad<<<dim3(16, 16), blk, 0, stream>>>(Wv, (unsigned short*)(wqkvT + 2 * 1024 * 1024), 1024, 1024, flag);
  transpose_ad<<<dim3(16, 16), blk, 0, stream>>>(Wo, (unsigned short*)woT, 1024, 1024, flag);
  transpose_ad<<<dim3(64, 16), blk, 0, stream>>>(fc1w, (unsigned short*)fc1T, 1024, 4096, flag);
  transpose_ad<<<dim3(16, 64), blk, 0, stream>>>(fc2w, (unsigned short*)fc2T, 4096, 1024, flag);

  ln_k<<<4096, blk, 0, stream>>>(x, ln1g, ln1b, h, flag, 0);

  gemm_bt<0><<<dim3(24, 32), blk, 0, stream>>>(h, wqkvT, 3072, 1024, nullptr, nullptr, nullptr, qkv, nullptr, flag);

  vtrans_k<<<dim3(32, 16, 2), blk, 0, stream>>>((const unsigned short*)qkv, (unsigned short*)vT);

  attn_k<<<dim3(32, 16, 2), blk, 0, stream>>>(qkv, vT, d_out, aout, flag);

  gemm_bt<2><<<dim3(8, 32), blk, 0, stream>>>(aout, woT, 1024, 1024, nullptr, x, nullptr, nullptr, x1, flag);

  ln_k<<<4096, blk, 0, stream>>>(x1, ln2g, ln2b, h, flag, 1);

  gemm_bt<1><<<dim3(32, 32), blk, 0, stream>>>(h, fc1T, 4096, 1024, fc1b, nullptr, nullptr, m1, nullptr, flag);

  gemm_bt<3><<<dim3(8, 32), blk, 0, stream>>>(m1, fc2T, 1024, 4096, fc2b, nullptr, x1, (bf16*)d_out, (float*)d_out, flag);
}

// Round 2
// 979.119 us; speedup vs baseline: 1.1801x; 1.0981x over previous
//
#include <hip/hip_runtime.h>
#include <cmath>

typedef __bf16 bf16;
typedef __bf16 bf16x8 __attribute__((ext_vector_type(8)));
typedef float f32x4 __attribute__((ext_vector_type(4)));

#define B_ 2
#define S_ 2048
#define D_ 1024
#define H_ 16
#define HD_ 64
#define MLP_ 4096
#define XOUT_ ((size_t)B_ * S_ * D_)   // 4194304 elements

#define SBAR() __builtin_amdgcn_s_barrier()
#define VMCNT(N) asm volatile("s_waitcnt vmcnt(" #N ")" ::: "memory")
#define SFENCE() asm volatile("" ::: "memory")

__device__ __forceinline__ void gll16(const void* g, void* l) {
  __builtin_amdgcn_global_load_lds((const __attribute__((address_space(1))) void*)g,
                                   (__attribute__((address_space(3))) void*)l, 16, 0, 0);
}

__device__ __forceinline__ f32x4 mfma16(bf16x8 a, bf16x8 b, f32x4 c) {
  return __builtin_amdgcn_mfma_f32_16x16x32_bf16(a, b, c, 0, 0, 0);
}

__device__ __forceinline__ float bfu2f(unsigned short u) {
  return __uint_as_float(((unsigned int)u) << 16);
}
__device__ __forceinline__ unsigned short f2bu(float v) {
  union { bf16 b; unsigned short u; } c; c.b = (bf16)v; return c.u;
}
__device__ __forceinline__ float ld_sc(const void* p, size_t i, int f32) {
  return f32 ? ((const float*)p)[i] : bfu2f(((const unsigned short*)p)[i]);
}

// XOR-swizzled element offset within a [rows][64] bf16 tile (row stride 128B).
__device__ __forceinline__ int swz(int row, int col) {
  int byo = row * 128 + col * 2;
  return (byo ^ (((byo >> 9) & 3) << 5)) >> 1;
}

// ---------------- dtype detector ----------------
__global__ __launch_bounds__(64) void detect_k(const unsigned short* __restrict__ x,
                                               int* __restrict__ flag) {
  int tid = threadIdx.x;
  int cnt = 0;
  for (int i = tid; i < 512; i += 64) {
    int e = (x[i] >> 7) & 0xFF;
    if (e >= 0xBF) cnt++;
  }
  #pragma unroll
  for (int d = 1; d < 64; d <<= 1) cnt += __shfl_xor(cnt, d);
  if (tid == 0) flag[0] = (cnt > 8) ? 1 : 0;
}

// ---------------- adaptive bf16 transpose (generic R,C) ----------------
__global__ __launch_bounds__(256) void transpose_ad(const void* __restrict__ in,
                                                    unsigned short* __restrict__ out,
                                                    int R, int C,
                                                    const int* __restrict__ flagp) {
  __shared__ unsigned short t[64][68];
  const int f32 = flagp[0];
  const int tid = threadIdx.x;
  const int c0 = blockIdx.x * 64, r0 = blockIdx.y * 64;
  for (int i = tid * 4; i < 4096; i += 1024) {
    int rr = i >> 6, cc = i & 63;
    size_t off = (size_t)(r0 + rr) * C + c0 + cc;
    if (f32) {
      float4 f = *(const float4*)((const float*)in + off);
      t[rr][cc + 0] = f2bu(f.x); t[rr][cc + 1] = f2bu(f.y);
      t[rr][cc + 2] = f2bu(f.z); t[rr][cc + 3] = f2bu(f.w);
    } else {
      *(ushort4*)&t[rr][cc] = *(const ushort4*)((const unsigned short*)in + off);
    }
  }
  __syncthreads();
  for (int i = tid * 4; i < 4096; i += 1024) {
    int orr = i & 63, oc = i >> 6;
    ushort4 v;
    v.x = t[orr + 0][oc]; v.y = t[orr + 1][oc];
    v.z = t[orr + 2][oc]; v.w = t[orr + 3][oc];
    *(ushort4*)(out + (size_t)(c0 + oc) * R + r0 + orr) = v;
  }
}

// ---------------- batched 1024x1024 transpose for Wq/Wk/Wv/Wo ----------------
__global__ __launch_bounds__(256) void transpose4_ad(const void* __restrict__ i0,
                                                     const void* __restrict__ i1,
                                                     const void* __restrict__ i2,
                                                     const void* __restrict__ i3,
                                                     unsigned short* __restrict__ wqkvT,
                                                     unsigned short* __restrict__ woT,
                                                     const int* __restrict__ flagp) {
  __shared__ unsigned short t[64][68];
  const int f32 = flagp[0];
  const int tid = threadIdx.x;
  const int z = blockIdx.z;
  const void* in = (z == 0) ? i0 : (z == 1) ? i1 : (z == 2) ? i2 : i3;
  unsigned short* out = (z < 3) ? (wqkvT + (size_t)z * 1024 * 1024) : woT;
  const int c0 = blockIdx.x * 64, r0 = blockIdx.y * 64;
  for (int i = tid * 4; i < 4096; i += 1024) {
    int rr = i >> 6, cc = i & 63;
    size_t off = (size_t)(r0 + rr) * 1024 + c0 + cc;
    if (f32) {
      float4 f = *(const float4*)((const float*)in + off);
      t[rr][cc + 0] = f2bu(f.x); t[rr][cc + 1] = f2bu(f.y);
      t[rr][cc + 2] = f2bu(f.z); t[rr][cc + 3] = f2bu(f.w);
    } else {
      *(ushort4*)&t[rr][cc] = *(const ushort4*)((const unsigned short*)in + off);
    }
  }
  __syncthreads();
  for (int i = tid * 4; i < 4096; i += 1024) {
    int orr = i & 63, oc = i >> 6;
    ushort4 v;
    v.x = t[orr + 0][oc]; v.y = t[orr + 1][oc];
    v.z = t[orr + 2][oc]; v.w = t[orr + 3][oc];
    *(ushort4*)(out + (size_t)(c0 + oc) * 1024 + r0 + orr) = v;
  }
}

// ---------------- V transpose ----------------
__global__ __launch_bounds__(256) void vtrans_k(const unsigned short* __restrict__ qkv,
                                                unsigned short* __restrict__ vT) {
  __shared__ unsigned short t[64][68];
  const int tid = threadIdx.x;
  const int s0 = blockIdx.x * 64, h = blockIdx.y, b = blockIdx.z;
  for (int i = tid * 4; i < 4096; i += 1024) {
    int si = i >> 6, hd = i & 63;
    *(ushort4*)&t[si][hd] =
        *(const ushort4*)(qkv + (size_t)(b * S_ + s0 + si) * 3072 + 2048 + h * 64 + hd);
  }
  __syncthreads();
  for (int i = tid * 4; i < 4096; i += 1024) {
    int ss = i & 63, hd = i >> 6;
    ushort4 v;
    v.x = t[ss + 0][hd]; v.y = t[ss + 1][hd];
    v.z = t[ss + 2][hd]; v.w = t[ss + 3][hd];
    *(ushort4*)(vT + ((size_t)(b * H_ + h) * 64 + hd) * S_ + s0 + ss) = v;
  }
}

// ---------------- LayerNorm ----------------
__global__ __launch_bounds__(256) void ln_k(const void* __restrict__ xv,
                                            const void* __restrict__ g,
                                            const void* __restrict__ bvec,
                                            bf16* __restrict__ out,
                                            const int* __restrict__ flagp,
                                            int force_xf32) {
  const int f32 = flagp[0];
  const int xf32 = force_xf32 ? 1 : f32;
  const int row = blockIdx.x, tid = threadIdx.x;
  float v[4];
  if (xf32) {
    float4 f = *(const float4*)((const float*)xv + (size_t)row * 1024 + tid * 4);
    v[0] = f.x; v[1] = f.y; v[2] = f.z; v[3] = f.w;
  } else {
    ushort4 u = *(const ushort4*)((const unsigned short*)xv + (size_t)row * 1024 + tid * 4);
    v[0] = bfu2f(u.x); v[1] = bfu2f(u.y); v[2] = bfu2f(u.z); v[3] = bfu2f(u.w);
  }
  float s = 0.f, q = 0.f;
  #pragma unroll
  for (int i = 0; i < 4; i++) { s += v[i]; q += v[i] * v[i]; }
  #pragma unroll
  for (int d = 1; d < 64; d <<= 1) { s += __shfl_xor(s, d); q += __shfl_xor(q, d); }
  __shared__ float red[8];
  if ((tid & 63) == 0) { red[(tid >> 6) * 2] = s; red[(tid >> 6) * 2 + 1] = q; }
  __syncthreads();
  s = red[0] + red[2] + red[4] + red[6];
  q = red[1] + red[3] + red[5] + red[7];
  const float mean = s * (1.0f / 1024.0f);
  const float var = q * (1.0f / 1024.0f) - mean * mean;
  const float rs = rsqrtf(var + 1e-5f);
  unsigned short ov[4];
  #pragma unroll
  for (int i = 0; i < 4; i++) {
    float gg = ld_sc(g, tid * 4 + i, f32);
    float bb = ld_sc(bvec, tid * 4 + i, f32);
    ov[i] = f2bu((v[i] - mean) * rs * gg + bb);
  }
  ushort4 o4; o4.x = ov[0]; o4.y = ov[1]; o4.z = ov[2]; o4.w = ov[3];
  *(ushort4*)((unsigned short*)out + (size_t)row * 1024 + tid * 4) = o4;
}

// ---------------- GEMM 128x128, BK=64, XCD-swizzled ----------------
template <int MODE>
__global__ __launch_bounds__(256) void gemm_bt(const bf16* __restrict__ A,
                                               const bf16* __restrict__ BT,
                                               int N, int K,
                                               const void* __restrict__ bias,
                                               const void* __restrict__ resb,
                                               const float* __restrict__ resf,
                                               bf16* __restrict__ outb,
                                               float* __restrict__ outf,
                                               const int* __restrict__ flagp) {
  __shared__ __align__(16) bf16 sA[128 * 64];
  __shared__ __align__(16) bf16 sB[128 * 64];
  const int f32 = flagp[0];
  const int tid = threadIdx.x;
  const int lane = tid & 63;
  const int wave = tid >> 6;
  const int wm = wave >> 1, wn = wave & 1;
  // XCD-aware bijective remap (nwg % 8 == 0 for all our grids)
  const int nwg = gridDim.x * gridDim.y;
  const int fid = blockIdx.y * gridDim.x + blockIdx.x;
  const int wg = ((nwg & 7) == 0) ? ((fid & 7) * (nwg >> 3) + (fid >> 3)) : fid;
  const int m0 = (wg / gridDim.x) * 128, n0 = (wg % gridDim.x) * 128;
  const int cn = lane & 15, rl = lane >> 4;
  const int r0 = tid >> 3, c16 = tid & 7;

  f32x4 zero = {0.f, 0.f, 0.f, 0.f};
  f32x4 acc[4][4];
  #pragma unroll
  for (int i = 0; i < 4; i++)
    #pragma unroll
    for (int j = 0; j < 4; j++) acc[i][j] = zero;

  for (int k0 = 0; k0 < K; k0 += 64) {
    __syncthreads();
    #pragma unroll
    for (int i = 0; i < 4; i++) {
      int row = r0 + i * 32;
      gll16(A + (size_t)(m0 + row) * K + k0 + c16 * 8, &sA[row * 64 + c16 * 8]);
      gll16(BT + (size_t)(n0 + row) * K + k0 + c16 * 8, &sB[row * 64 + c16 * 8]);
    }
    __syncthreads();
    #pragma unroll
    for (int kk = 0; kk < 64; kk += 32) {
      bf16x8 af[4], bfr[4];
      #pragma unroll
      for (int t = 0; t < 4; t++) {
        af[t] = *(const bf16x8*)&sA[(wm * 64 + t * 16 + cn) * 64 + kk + rl * 8];
        bfr[t] = *(const bf16x8*)&sB[(wn * 64 + t * 16 + cn) * 64 + kk + rl * 8];
      }
      #pragma unroll
      for (int mt = 0; mt < 4; mt++)
        #pragma unroll
        for (int nt = 0; nt < 4; nt++)
          acc[mt][nt] = mfma16(af[mt], bfr[nt], acc[mt][nt]);
    }
  }

  #pragma unroll
  for (int mt = 0; mt < 4; mt++) {
    #pragma unroll
    for (int nt = 0; nt < 4; nt++) {
      #pragma unroll
      for (int j = 0; j < 4; j++) {
        const int row = m0 + wm * 64 + mt * 16 + rl * 4 + j;
        const int col = n0 + wn * 64 + nt * 16 + cn;
        const size_t idx = (size_t)row * N + col;
        float v = acc[mt][nt][j];
        if (MODE == 0) {
          outb[idx] = (bf16)v;
        } else if (MODE == 1) {
          v += ld_sc(bias, col, f32);
          float u = 0.7978845608028654f * (v + 0.044715f * v * v * v);
          float gl = v / (1.0f + exp2f(-2.8853900817779268f * u));
          outb[idx] = (bf16)gl;
        } else if (MODE == 2) {
          outf[idx] = v + ld_sc(resb, idx, f32);
        } else {
          float val = v + ld_sc(bias, col, f32) + resf[idx];
          if (f32) outf[idx] = val; else outb[idx] = (bf16)val;
        }
      }
    }
  }
}

// ---------------- GEMM 128x64 (for narrow-N: Wo, fc2) — 2x blocks/CU ----------------
template <int MODE>
__global__ __launch_bounds__(256) void gemm_n64(const bf16* __restrict__ A,
                                                const bf16* __restrict__ BT,
                                                int N, int K,
                                                const void* __restrict__ bias,
                                                const void* __restrict__ resb,
                                                const float* __restrict__ resf,
                                                bf16* __restrict__ outb,
                                                float* __restrict__ outf,
                                                const int* __restrict__ flagp) {
  __shared__ __align__(16) bf16 sA[128 * 64];
  __shared__ __align__(16) bf16 sB[64 * 64];
  const int f32 = flagp[0];
  const int tid = threadIdx.x;
  const int lane = tid & 63;
  const int wave = tid >> 6;
  const int nwg = gridDim.x * gridDim.y;
  const int fid = blockIdx.y * gridDim.x + blockIdx.x;
  const int wg = ((nwg & 7) == 0) ? ((fid & 7) * (nwg >> 3) + (fid >> 3)) : fid;
  const int m0 = (wg / gridDim.x) * 128, n0 = (wg % gridDim.x) * 64;
  const int cn = lane & 15, rl = lane >> 4;
  const int r0 = tid >> 3, c16 = tid & 7;

  f32x4 zero = {0.f, 0.f, 0.f, 0.f};
  f32x4 acc[2][4];
  #pragma unroll
  for (int i = 0; i < 2; i++)
    #pragma unroll
    for (int j = 0; j < 4; j++) acc[i][j] = zero;

  for (int k0 = 0; k0 < K; k0 += 64) {
    __syncthreads();
    #pragma unroll
    for (int i = 0; i < 4; i++) {
      int row = r0 + i * 32;
      gll16(A + (size_t)(m0 + row) * K + k0 + c16 * 8, &sA[row * 64 + c16 * 8]);
    }
    #pragma unroll
    for (int i = 0; i < 2; i++) {
      int row = r0 + i * 32;
      gll16(BT + (size_t)(n0 + row) * K + k0 + c16 * 8, &sB[row * 64 + c16 * 8]);
    }
    __syncthreads();
    #pragma unroll
    for (int kk = 0; kk < 64; kk += 32) {
      bf16x8 af[2], bfr[4];
      #pragma unroll
      for (int t = 0; t < 2; t++)
        af[t] = *(const bf16x8*)&sA[(wave * 32 + t * 16 + cn) * 64 + kk + rl * 8];
      #pragma unroll
      for (int t = 0; t < 4; t++)
        bfr[t] = *(const bf16x8*)&sB[(t * 16 + cn) * 64 + kk + rl * 8];
      #pragma unroll
      for (int mt = 0; mt < 2; mt++)
        #pragma unroll
        for (int nt = 0; nt < 4; nt++)
          acc[mt][nt] = mfma16(af[mt], bfr[nt], acc[mt][nt]);
    }
  }

  #pragma unroll
  for (int mt = 0; mt < 2; mt++) {
    #pragma unroll
    for (int nt = 0; nt < 4; nt++) {
      #pragma unroll
      for (int j = 0; j < 4; j++) {
        const int row = m0 + wave * 32 + mt * 16 + rl * 4 + j;
        const int col = n0 + nt * 16 + cn;
        const size_t idx = (size_t)row * N + col;
        float v = acc[mt][nt][j];
        if (MODE == 2) {
          outf[idx] = v + ld_sc(resb, idx, f32);
        } else {
          float val = v + ld_sc(bias, col, f32) + resf[idx];
          if (f32) outf[idx] = val; else outb[idx] = (bf16)val;
        }
      }
    }
  }
}

// ---------------- Attention ----------------
// flat grid 1024: XCD c (= fid%8) owns (h,b) pairs {c, c+8, c+16, c+24} -> KV L2-resident
__global__ __launch_bounds__(256) void attn_k(const bf16* __restrict__ qkv,
                                              const bf16* __restrict__ vT,
                                              void* __restrict__ Pv,
                                              bf16* __restrict__ ao,
                                              const int* __restrict__ flagp) {
  __shared__ __align__(16) bf16 sKV[4][64 * 64];  // pass1: 4-slot K ring; pass2: K=[cur], V=[2+cur]
  __shared__ __align__(16) bf16 sP[4][16 * 64];   // LDS total 40960B -> 4 blocks/CU
  const int f32o = flagp[0];
  const int tid = threadIdx.x, lane = tid & 63, wave = tid >> 6;
  const int fid = blockIdx.x;
  const int c8 = fid & 7, kk8 = fid >> 3;
  const int qt = 31 - (kk8 & 31);              // LPT within each XCD stream
  const int p = c8 + 8 * (kk8 >> 5);           // (h,b) pair in [0,32)
  const int h = p & 15, b = p >> 4;
  const float scale2 = 0.18033688011112042f;   // 0.125 * log2(e)
  const float NEG = -1e30f;
  const int cn = lane & 15, rl = lane >> 4;

  int urow[2], ucol[2], ldst[2];
  #pragma unroll
  for (int i = 0; i < 2; i++) {
    int Lb = tid * 16 + i * 4096;
    int Ub = Lb ^ (((Lb >> 9) & 3) << 5);
    urow[i] = Ub >> 7;
    ucol[i] = (Ub & 127) >> 1;
    ldst[i] = Lb >> 1;
  }

  const bf16* kbase = qkv + (size_t)b * S_ * 3072 + 1024 + h * 64;
  const bf16* vbase = vT + ((size_t)(b * H_ + h) * 64) * S_;

  bf16x8 aq[2];
  {
    const bf16* qb = qkv + (size_t)(b * S_ + qt * 64 + wave * 16 + cn) * 3072 + h * 64;
    aq[0] = *(const bf16x8*)(qb + rl * 8);
    aq[1] = *(const bf16x8*)(qb + 32 + rl * 8);
  }

#define STAGEK(kt_, s_) { \
    _Pragma("unroll") for (int i = 0; i < 2; i++) \
      gll16(kbase + (size_t)((kt_) * 64 + urow[i]) * 3072 + ucol[i], &sKV[s_][ldst[i]]); }
#define STAGEV(kt_, s_) { \
    _Pragma("unroll") for (int i = 0; i < 2; i++) \
      gll16(vbase + (size_t)urow[i] * S_ + (kt_) * 64 + ucol[i], &sKV[s_][ldst[i]]); }

  // ---- pass 1: per-lane online softmax, depth-2 K prefetch over 4 slots
  float m_i[4], l_i[4];
  #pragma unroll
  for (int j = 0; j < 4; j++) { m_i[j] = NEG; l_i[j] = 0.0f; }

  STAGEK(0, 0);
  if (qt >= 1) { STAGEK(1, 1); SFENCE(); VMCNT(2); } else { VMCNT(0); }
  SBAR();

  for (int kt = 0; kt <= qt; kt++) {
    if (kt + 2 <= qt) { STAGEK(kt + 2, ((kt + 2) & 3)); SFENCE(); }
    const int slot = kt & 3;
    f32x4 s4[4];
    f32x4 zero = {0.f, 0.f, 0.f, 0.f};
    #pragma unroll
    for (int nt = 0; nt < 4; nt++) s4[nt] = zero;
    #pragma unroll
    for (int kx = 0; kx < 2; kx++)
      #pragma unroll
      for (int nt = 0; nt < 4; nt++) {
        bf16x8 bb = *(const bf16x8*)&sKV[slot][swz(nt * 16 + cn, kx * 32 + rl * 8)];
        s4[nt] = mfma16(aq[kx], bb, s4[nt]);
      }
    if (kt == qt) {
      #pragma unroll
      for (int nt = 0; nt < 4; nt++)
        #pragma unroll
        for (int j = 0; j < 4; j++)
          s4[nt][j] = (nt * 16 + cn > wave * 16 + rl * 4 + j) ? NEG : s4[nt][j] * scale2;
    } else {
      #pragma unroll
      for (int nt = 0; nt < 4; nt++)
        #pragma unroll
        for (int j = 0; j < 4; j++) s4[nt][j] *= scale2;
    }
    // per-lane online update: NO cross-lane ops per tile
    #pragma unroll
    for (int j = 0; j < 4; j++) {
      float pm = fmaxf(fmaxf(s4[0][j], s4[1][j]), fmaxf(s4[2][j], s4[3][j]));
      float mn = fmaxf(m_i[j], pm);
      float ps = exp2f(s4[0][j] - mn) + exp2f(s4[1][j] - mn) +
                 exp2f(s4[2][j] - mn) + exp2f(s4[3][j] - mn);
      l_i[j] = l_i[j] * exp2f(m_i[j] - mn) + ps;
      m_i[j] = mn;
    }
    if (kt < qt) {
      if (kt + 2 <= qt) { VMCNT(2); } else { VMCNT(0); }
      SBAR();
    }
  }

  // cross-lane combine, once: lanes with m=-1e30 contribute l*exp2(-huge)=0
  #pragma unroll
  for (int j = 0; j < 4; j++) {
    float mr = m_i[j];
    #pragma unroll
    for (int d = 1; d < 16; d <<= 1) mr = fmaxf(mr, __shfl_xor(mr, d));
    float lr = l_i[j] * exp2f(m_i[j] - mr);
    #pragma unroll
    for (int d = 1; d < 16; d <<= 1) lr += __shfl_xor(lr, d);
    m_i[j] = mr;
    l_i[j] = lr;
  }

  float inv_l[4];
  #pragma unroll
  for (int j = 0; j < 4; j++) inv_l[j] = 1.0f / l_i[j];

  // ---- pass 2
  SBAR();  // all waves finished pass-1 LDS reads (uses precede this barrier)
  STAGEK(0, 0);
  STAGEV(0, 2);
  VMCNT(0);
  SBAR();
  int cur = 0;

  f32x4 o[4];
  {
    f32x4 zero = {0.f, 0.f, 0.f, 0.f};
    #pragma unroll
    for (int nt = 0; nt < 4; nt++) o[nt] = zero;
  }

  for (int kt = 0; kt <= qt; kt++) {
    if (kt < qt) {
      STAGEK(kt + 1, (cur ^ 1));
      STAGEV(kt + 1, (2 + (cur ^ 1)));
      SFENCE();  // pin the 4 stage loads first in the vmcnt FIFO
    }
    f32x4 s4[4];
    f32x4 zero = {0.f, 0.f, 0.f, 0.f};
    #pragma unroll
    for (int nt = 0; nt < 4; nt++) s4[nt] = zero;
    #pragma unroll
    for (int kx = 0; kx < 2; kx++)
      #pragma unroll
      for (int nt = 0; nt < 4; nt++) {
        bf16x8 bb = *(const bf16x8*)&sKV[cur][swz(nt * 16 + cn, kx * 32 + rl * 8)];
        s4[nt] = mfma16(aq[kx], bb, s4[nt]);
      }
    if (kt == qt) {
      #pragma unroll
      for (int nt = 0; nt < 4; nt++)
        #pragma unroll
        for (int j = 0; j < 4; j++) {
          bool masked = (nt * 16 + cn > wave * 16 + rl * 4 + j);
          float pv = masked ? 0.0f : exp2f(s4[nt][j] * scale2 - m_i[j]) * inv_l[j];
          sP[wave][swz(rl * 4 + j, nt * 16 + cn)] = (bf16)pv;
        }
    } else {
      #pragma unroll
      for (int nt = 0; nt < 4; nt++)
        #pragma unroll
        for (int j = 0; j < 4; j++) {
          float pv = exp2f(s4[nt][j] * scale2 - m_i[j]) * inv_l[j];
          sP[wave][swz(rl * 4 + j, nt * 16 + cn)] = (bf16)pv;
        }
    }
    // P tile -> global (stores drain under PV compute)
    {
      size_t base = XOUT_ + (((size_t)b * H_ + h) * S_ + qt * 64 + wave * 16) * S_ + kt * 64;
      #pragma unroll
      for (int i = 0; i < 2; i++) {
        int idx = lane + i * 64;
        int r = idx >> 3, cc = idx & 7;
        uint4 val = *(const uint4*)&sP[wave][swz(r, cc * 8)];
        if (f32o) {
          float4 lo, hi;
          lo.x = __uint_as_float(val.x << 16); lo.y = __uint_as_float(val.x & 0xffff0000u);
          lo.z = __uint_as_float(val.y << 16); lo.w = __uint_as_float(val.y & 0xffff0000u);
          hi.x = __uint_as_float(val.z << 16); hi.y = __uint_as_float(val.z & 0xffff0000u);
          hi.z = __uint_as_float(val.w << 16); hi.w = __uint_as_float(val.w & 0xffff0000u);
          *(float4*)((float*)Pv + base + (size_t)r * S_ + cc * 8) = lo;
          *(float4*)((float*)Pv + base + (size_t)r * S_ + cc * 8 + 4) = hi;
        } else {
          *(uint4*)((bf16*)Pv + base + (size_t)r * S_ + cc * 8) = val;
        }
      }
    }
    // PV
    #pragma unroll
    for (int kx = 0; kx < 2; kx++) {
      bf16x8 ap = *(const bf16x8*)&sP[wave][swz(cn, kx * 32 + rl * 8)];
      #pragma unroll
      for (int nt = 0; nt < 4; nt++) {
        bf16x8 bv = *(const bf16x8*)&sKV[2 + cur][swz(nt * 16 + cn, kx * 32 + rl * 8)];
        o[nt] = mfma16(ap, bv, o[nt]);
      }
    }
    if (kt < qt) {
      if (f32o) { VMCNT(4); } else { VMCNT(2); }
      SBAR();
      cur ^= 1;
    }
  }

  // zero-fill strictly-above-diagonal tiles
  {
    const int t0 = qt + 1;
    const int nch = (32 - t0) * 8;
    size_t rowbase = XOUT_ + (((size_t)b * H_ + h) * S_ + qt * 64) * S_;
    uint4 z; z.x = 0; z.y = 0; z.z = 0; z.w = 0;
    for (int idx = tid; idx < 64 * nch; idx += 256) {
      int r = idx / nch, cc = idx % nch;
      size_t off = rowbase + (size_t)r * S_ + t0 * 64 + cc * 8;
      if (f32o) {
        *(uint4*)((float*)Pv + off) = z;
        *(uint4*)((float*)Pv + off + 4) = z;
      } else {
        *(uint4*)((bf16*)Pv + off) = z;
      }
    }
  }

  // write O (internal, bf16)
  #pragma unroll
  for (int nt = 0; nt < 4; nt++)
    #pragma unroll
    for (int j = 0; j < 4; j++) {
      int rowg2 = b * S_ + qt * 64 + wave * 16 + rl * 4 + j;
      ao[(size_t)rowg2 * 1024 + h * 64 + nt * 16 + cn] = (bf16)o[nt][j];
    }
#undef STAGEK
#undef STAGEV
}

extern "C" void kernel_launch(void* const* d_in, const int* in_sizes, int n_in,
                              void* d_out, int out_size, void* d_ws, size_t ws_size,
                              hipStream_t stream) {
  (void)in_sizes; (void)n_in; (void)out_size; (void)ws_size;
  const void* x    = d_in[0];
  const void* ln1g = d_in[1];
  const void* ln1b = d_in[2];
  const void* Wq   = d_in[3];
  const void* Wk   = d_in[4];
  const void* Wv   = d_in[5];
  const void* Wo   = d_in[6];
  const void* ln2g = d_in[7];
  const void* ln2b = d_in[8];
  const void* fc1w = d_in[9];
  const void* fc1b = d_in[10];
  const void* fc2w = d_in[11];
  const void* fc2b = d_in[12];

  char* ws = (char*)d_ws;
  bf16* wqkvT = (bf16*)(ws + 0);
  bf16* woT   = (bf16*)(ws + 6291456);
  bf16* fc1T  = (bf16*)(ws + 8388608);
  bf16* fc2T  = (bf16*)(ws + 16777216);
  bf16* h     = (bf16*)(ws + 25165824);
  bf16* qkv   = (bf16*)(ws + 33554432);
  bf16* vT    = (bf16*)(ws + 58720256);
  bf16* m1    = (bf16*)(ws + 33554432);
  bf16* aout  = (bf16*)(ws + 67108864);
  float* x1   = (float*)(ws + 75497472);
  int* flag   = (int*)(ws + 92274688);

  dim3 blk(256);

  detect_k<<<1, 64, 0, stream>>>((const unsigned short*)x, flag);

  transpose4_ad<<<dim3(16, 16, 4), blk, 0, stream>>>(Wq, Wk, Wv, Wo,
      (unsigned short*)wqkvT, (unsigned short*)woT, flag);
  transpose_ad<<<dim3(64, 16), blk, 0, stream>>>(fc1w, (unsigned short*)fc1T, 1024, 4096, flag);
  transpose_ad<<<dim3(16, 64), blk, 0, stream>>>(fc2w, (unsigned short*)fc2T, 4096, 1024, flag);

  ln_k<<<4096, blk, 0, stream>>>(x, ln1g, ln1b, h, flag, 0);

  gemm_bt<0><<<dim3(24, 32), blk, 0, stream>>>(h, wqkvT, 3072, 1024, nullptr, nullptr, nullptr, qkv, nullptr, flag);

  vtrans_k<<<dim3(32, 16, 2), blk, 0, stream>>>((const unsigned short*)qkv, (unsigned short*)vT);

  attn_k<<<dim3(1024), blk, 0, stream>>>(qkv, vT, d_out, aout, flag);

  gemm_n64<2><<<dim3(16, 32), blk, 0, stream>>>(aout, woT, 1024, 1024, nullptr, x, nullptr, nullptr, x1, flag);

  ln_k<<<4096, blk, 0, stream>>>(x1, ln2g, ln2b, h, flag, 1);

  gemm_bt<1><<<dim3(32, 32), blk, 0, stream>>>(h, fc1T, 4096, 1024, fc1b, nullptr, nullptr, m1, nullptr, flag);

  gemm_n64<3><<<dim3(16, 32), blk, 0, stream>>>(m1, fc2T, 1024, 4096, fc2b, nullptr, x1, (bf16*)d_out, (float*)d_out, flag);
}